// Round 1
// baseline (359.607 us; speedup 1.0000x reference)
//
#include <hip/hip_runtime.h>

typedef _Float16 f16;
typedef _Float16 half8 __attribute__((ext_vector_type(8)));
typedef _Float16 f16x4 __attribute__((ext_vector_type(4)));
typedef float    floatx4 __attribute__((ext_vector_type(4)));
typedef float    f32x4 __attribute__((ext_vector_type(4)));

#define L_SEQ 4096
#define DM    768
#define NQ    8
#define QD    96
#define WIN   128
#define NPAD  1024   // padded qkv column count (960 -> 1024)

// ---------------------------------------------------------------------------
// async global->LDS copy, 16B per lane (guide §5: width=16 is the fast path)
// ---------------------------------------------------------------------------
__device__ __forceinline__ void async_copy16(const f16* g, f16* l) {
  __builtin_amdgcn_global_load_lds((const __attribute__((address_space(1))) void*)g,
                                   (__attribute__((address_space(3))) void*)l,
                                   16, 0, 0);
}

// ---------------------------------------------------------------------------
// cast x (4096x768 f32) -> f16
// ---------------------------------------------------------------------------
__global__ __launch_bounds__(256) void cast_x_kernel(const float* __restrict__ x,
                                                     f16* __restrict__ xh) {
  int idx = blockIdx.x * 256 + threadIdx.x;   // one f32x4 per thread
  f32x4 v = ((const f32x4*)x)[idx];
  f16x4 o;
  o[0] = (f16)v[0]; o[1] = (f16)v[1]; o[2] = (f16)v[2]; o[3] = (f16)v[3];
  ((f16x4*)xh)[idx] = o;
}

// ---------------------------------------------------------------------------
// cast Wqkv (960x768 -> padded 1024x768 f16, zero rows past 960),
// cast Wout (768x768 f16), pad bqkv -> 1024 f32
// ---------------------------------------------------------------------------
__global__ __launch_bounds__(256) void prep_w_kernel(const float* __restrict__ Wqkv,
                                                     const float* __restrict__ bqkv,
                                                     const float* __restrict__ Wout,
                                                     f16* __restrict__ w1h,
                                                     f16* __restrict__ w2h,
                                                     float* __restrict__ b1p) {
  const int NW1 = 1024 * 768 / 4;   // 196608
  const int NW2 = 768 * 768 / 4;    // 147456
  int idx = blockIdx.x * 256 + threadIdx.x;
  if (idx < NW1) {
    int r = idx / 192;              // 192 f32x4 per 768-row
    f16x4 o;
    if (r < 960) {
      f32x4 v = ((const f32x4*)Wqkv)[idx];
      o[0] = (f16)v[0]; o[1] = (f16)v[1]; o[2] = (f16)v[2]; o[3] = (f16)v[3];
    } else {
      o[0] = (f16)0.f; o[1] = (f16)0.f; o[2] = (f16)0.f; o[3] = (f16)0.f;
    }
    ((f16x4*)w1h)[idx] = o;
  } else if (idx < NW1 + NW2) {
    int j = idx - NW1;
    f32x4 v = ((const f32x4*)Wout)[j];
    f16x4 o;
    o[0] = (f16)v[0]; o[1] = (f16)v[1]; o[2] = (f16)v[2]; o[3] = (f16)v[3];
    ((f16x4*)w2h)[j] = o;
  } else {
    int j = idx - (NW1 + NW2);      // 0..1023
    b1p[j] = (j < 960) ? bqkv[j] : 0.f;
  }
}

// ---------------------------------------------------------------------------
// GEMM: C[M x ldc](f32) = A[M x K](f16, row-major) * B[N x K](f16, row-major)^T + bias
// 128x128 tile, BK=32, 4 waves, mfma_f32_16x16x32_f16, global_load_lds staging.
// Requires M%128==0, N%128==0, K%32==0.
// ---------------------------------------------------------------------------
__global__ __launch_bounds__(256) void gemm_f16_tn(const f16* __restrict__ A,
                                                   const f16* __restrict__ B,
                                                   const float* __restrict__ bias,
                                                   float* __restrict__ C,
                                                   int K, int ldc) {
  __shared__ f16 As[128 * 32];
  __shared__ f16 Bs[128 * 32];
  const int t  = threadIdx.x;
  const int bm = blockIdx.y * 128;
  const int bn = blockIdx.x * 128;
  const int w  = t >> 6, l = t & 63;
  const int wr = w >> 1, wc = w & 1;

  floatx4 acc[4][4] = {};

  // staging: per issue s (0,1): row = s*64 + t/4, k-chunk = (t%4)*8
  const f16* Ap = A + (size_t)(bm + (t >> 2)) * K + (t & 3) * 8;
  const f16* Bp = B + (size_t)(bn + (t >> 2)) * K + (t & 3) * 8;
  f16* lA = &As[t * 8];
  f16* lB = &Bs[t * 8];

  const int fr = l & 15;   // row/col within 16x16 fragment
  const int kg = l >> 4;   // k-group (8 halves each)

  for (int k0 = 0; k0 < K; k0 += 32) {
    __syncthreads();                       // previous tile fully consumed
    async_copy16(Ap + k0,          lA);
    async_copy16(Ap + 64 * K + k0, lA + 2048);
    async_copy16(Bp + k0,          lB);
    async_copy16(Bp + 64 * K + k0, lB + 2048);
    __syncthreads();                       // staging drained (vmcnt(0) at barrier)

    half8 a[4], b[4];
#pragma unroll
    for (int m = 0; m < 4; ++m)
      a[m] = *(const half8*)&As[(wr * 64 + m * 16 + fr) * 32 + kg * 8];
#pragma unroll
    for (int n = 0; n < 4; ++n)
      b[n] = *(const half8*)&Bs[(wc * 64 + n * 16 + fr) * 32 + kg * 8];
#pragma unroll
    for (int m = 0; m < 4; ++m)
#pragma unroll
      for (int n = 0; n < 4; ++n)
        acc[m][n] = __builtin_amdgcn_mfma_f32_16x16x32_f16(a[m], b[n], acc[m][n], 0, 0, 0);
  }

  // epilogue: C/D layout col = lane&15, row = (lane>>4)*4 + reg
  const int r0 = (l >> 4) * 4;
#pragma unroll
  for (int n = 0; n < 4; ++n) {
    int col = bn + wc * 64 + n * 16 + fr;
    float bv = bias[col];
#pragma unroll
    for (int m = 0; m < 4; ++m) {
      int row = bm + wr * 64 + m * 16 + r0;
#pragma unroll
      for (int r = 0; r < 4; ++r)
        C[(size_t)(row + r) * ldc + col] = acc[m][n][r] + bv;
    }
  }
}

// ---------------------------------------------------------------------------
// RoPE in place on qkv (f32, ld NPAD): k cols [0,96), q cols [192,960).
// One block per position. cos/sin computed once per (pos,freq) in LDS.
// ---------------------------------------------------------------------------
__global__ __launch_bounds__(256) void rope_kernel(float* __restrict__ qkv) {
  __shared__ float cs[48], sn[48];
  const int i = blockIdx.x;
  const int t = threadIdx.x;
  if (t < 48) {
    float theta = powf(10000.f, -(float)(2 * t) / 96.f);
    float ang = (float)i * theta;
    float s, c;
    sincosf(ang, &s, &c);
    cs[t] = c; sn[t] = s;
  }
  __syncthreads();
  float* row = qkv + (size_t)i * NPAD;
  for (int p = t; p < 432; p += 256) {     // 48 k-pairs + 8*48 q-pairs
    int seg = p / 48;                      // 0 = k, 1..8 = q heads
    int f   = p - seg * 48;
    int base = (seg == 0) ? 0 : 96 * (seg + 1);   // k at 0, q head h at 192+96h
    int ce = base + 2 * f, co = ce + 1;
    float e = row[ce], o = row[co];
    float c = cs[f], s = sn[f];
    row[ce] = e * c - o * s;
    row[co] = e * s + o * c;
  }
}

// ---------------------------------------------------------------------------
// Windowed causal attention, fp32. One wave per (query i, head h).
// Lane l handles keys j = i-l and j = i-64-l. p transposed via LDS for PV.
// Writes attention output as f16 in (L, 8*96) layout.
// ---------------------------------------------------------------------------
__global__ __launch_bounds__(256) void attn_kernel(const float* __restrict__ qkv,
                                                   f16* __restrict__ aout) {
  __shared__ float plds[4][128];
  const int i = blockIdx.x >> 1;
  const int w = threadIdx.x >> 6;
  const int l = threadIdx.x & 63;
  const int h = ((blockIdx.x & 1) << 2) | w;

  const float* qrow = qkv + (size_t)i * NPAD + 2 * QD + h * QD;
  const int ja = i - l;
  const int jb = i - 64 - l;
  const float* ka = qkv + (size_t)(ja < 0 ? 0 : ja) * NPAD;
  const float* kb = qkv + (size_t)(jb < 0 ? 0 : jb) * NPAD;

  float sa = 0.f, sb = 0.f;
#pragma unroll
  for (int d = 0; d < QD; d += 4) {
    f32x4 q  = *(const f32x4*)(qrow + d);
    f32x4 va = *(const f32x4*)(ka + d);
    f32x4 vb = *(const f32x4*)(kb + d);
    sa += q[0] * va[0] + q[1] * va[1] + q[2] * va[2] + q[3] * va[3];
    sb += q[0] * vb[0] + q[1] * vb[1] + q[2] * vb[2] + q[3] * vb[3];
  }
  const float scale = 9.79795897113271f;   // sqrt(96)
  sa = (ja >= 0) ? sa * scale : -1e30f;
  sb = (jb >= 0) ? sb * scale : -1e30f;

  float mx = fmaxf(sa, sb);
#pragma unroll
  for (int off = 32; off > 0; off >>= 1)
    mx = fmaxf(mx, __shfl_xor(mx, off));
  float pa = (ja >= 0) ? __expf(sa - mx) : 0.f;
  float pb = (jb >= 0) ? __expf(sb - mx) : 0.f;
  float sum = pa + pb;
#pragma unroll
  for (int off = 32; off > 0; off >>= 1)
    sum += __shfl_xor(sum, off);
  float inv = 1.f / sum;

  plds[w][l]      = pa * inv;
  plds[w][64 + l] = pb * inv;
  __syncthreads();

  const int nk = (i + 1 < WIN) ? (i + 1) : WIN;
  const float* vbase = qkv + (size_t)i * NPAD + QD;   // v of row i
  float acc0 = 0.f, acc1 = 0.f;
#pragma unroll 4
  for (int jj = 0; jj < nk; ++jj) {
    float p = plds[w][jj];
    const float* vr = vbase - (size_t)jj * NPAD;      // v of row i-jj
    acc0 += p * vr[l];
    if (l < 32) acc1 += p * vr[64 + l];
  }

  f16* orow = aout + (size_t)i * DM + h * QD;
  orow[l] = (f16)acc0;
  if (l < 32) orow[64 + l] = (f16)acc1;
}

// ---------------------------------------------------------------------------
extern "C" void kernel_launch(void* const* d_in, const int* in_sizes, int n_in,
                              void* d_out, int out_size, void* d_ws, size_t ws_size,
                              hipStream_t stream) {
  const float* x    = (const float*)d_in[0];
  const float* Wqkv = (const float*)d_in[1];
  const float* bqkv = (const float*)d_in[2];
  const float* Wout = (const float*)d_in[3];
  const float* bout = (const float*)d_in[4];
  float* out = (float*)d_out;

  char* ws = (char*)d_ws;
  f16*   xh   = (f16*)(ws);                          // 4096*768*2   = 6291456
  f16*   w1h  = (f16*)(ws + 6291456);                // 1024*768*2   = 1572864
  f16*   w2h  = (f16*)(ws + 7864320);                // 768*768*2    = 1179648
  float* b1p  = (float*)(ws + 9043968);              // 1024*4       = 4096
  float* qkv  = (float*)(ws + 9048064);              // 4096*1024*4  = 16777216
  f16*   aout = (f16*)(ws + 25825280);               // 4096*768*2   = 6291456
  // total: 32116736 bytes

  cast_x_kernel<<<dim3(3072), dim3(256), 0, stream>>>(x, xh);
  prep_w_kernel<<<dim3(1348), dim3(256), 0, stream>>>(Wqkv, bqkv, Wout, w1h, w2h, b1p);
  gemm_f16_tn<<<dim3(8, 32), dim3(256), 0, stream>>>(xh, w1h, b1p, qkv, 768, 1024);
  rope_kernel<<<dim3(4096), dim3(256), 0, stream>>>(qkv);
  attn_kernel<<<dim3(8192), dim3(256), 0, stream>>>(qkv, aout);
  gemm_f16_tn<<<dim3(6, 32), dim3(256), 0, stream>>>(aout, w2h, bout, out, 768, 768);
}

// Round 2
// 113.082 us; speedup vs baseline: 3.1801x; 3.1801x over previous
//
#include <hip/hip_runtime.h>

typedef _Float16 f16;
typedef _Float16 half8 __attribute__((ext_vector_type(8)));
typedef _Float16 f16x2 __attribute__((ext_vector_type(2)));
typedef _Float16 f16x4 __attribute__((ext_vector_type(4)));
typedef float    f32x4 __attribute__((ext_vector_type(4)));

#define DM    768
#define QD    96
#define NPAD  1024
#define MFMA16(a,b,c) __builtin_amdgcn_mfma_f32_16x16x32_f16(a, b, c, 0, 0, 0)

// ---------------------------------------------------------------------------
__device__ __forceinline__ void async_copy16(const f16* g, f16* l) {
  __builtin_amdgcn_global_load_lds((const __attribute__((address_space(1))) void*)g,
                                   (__attribute__((address_space(3))) void*)l,
                                   16, 0, 0);
}

// ---------------------------------------------------------------------------
// cast x (4096x768 f32) -> f16
// ---------------------------------------------------------------------------
__global__ __launch_bounds__(256) void cast_x_kernel(const float* __restrict__ x,
                                                     f16* __restrict__ xh) {
  int idx = blockIdx.x * 256 + threadIdx.x;
  f32x4 v = ((const f32x4*)x)[idx];
  f16x4 o;
  o[0] = (f16)v[0]; o[1] = (f16)v[1]; o[2] = (f16)v[2]; o[3] = (f16)v[3];
  ((f16x4*)xh)[idx] = o;
}

// ---------------------------------------------------------------------------
// cast Wqkv (960x768 -> padded 1024x768 f16), Wout (768x768 f16), pad bqkv
// ---------------------------------------------------------------------------
__global__ __launch_bounds__(256) void prep_w_kernel(const float* __restrict__ Wqkv,
                                                     const float* __restrict__ bqkv,
                                                     const float* __restrict__ Wout,
                                                     f16* __restrict__ w1h,
                                                     f16* __restrict__ w2h,
                                                     float* __restrict__ b1p) {
  const int NW1 = 1024 * 768 / 4;
  const int NW2 = 768 * 768 / 4;
  int idx = blockIdx.x * 256 + threadIdx.x;
  if (idx < NW1) {
    int r = idx / 192;
    f16x4 o;
    if (r < 960) {
      f32x4 v = ((const f32x4*)Wqkv)[idx];
      o[0] = (f16)v[0]; o[1] = (f16)v[1]; o[2] = (f16)v[2]; o[3] = (f16)v[3];
    } else {
      o[0] = (f16)0.f; o[1] = (f16)0.f; o[2] = (f16)0.f; o[3] = (f16)0.f;
    }
    ((f16x4*)w1h)[idx] = o;
  } else if (idx < NW1 + NW2) {
    int j = idx - NW1;
    f32x4 v = ((const f32x4*)Wout)[j];
    f16x4 o;
    o[0] = (f16)v[0]; o[1] = (f16)v[1]; o[2] = (f16)v[2]; o[3] = (f16)v[3];
    ((f16x4*)w2h)[j] = o;
  } else {
    int j = idx - (NW1 + NW2);
    b1p[j] = (j < 960) ? bqkv[j] : 0.f;
  }
}

// ---------------------------------------------------------------------------
// GEMM: C[M x ldc](f32) = A[M x K](f16) * B[N x K](f16)^T + bias
// ---------------------------------------------------------------------------
__global__ __launch_bounds__(256) void gemm_f16_tn(const f16* __restrict__ A,
                                                   const f16* __restrict__ B,
                                                   const float* __restrict__ bias,
                                                   float* __restrict__ C,
                                                   int K, int ldc) {
  __shared__ f16 As[128 * 32];
  __shared__ f16 Bs[128 * 32];
  const int t  = threadIdx.x;
  const int bm = blockIdx.y * 128;
  const int bn = blockIdx.x * 128;
  const int w  = t >> 6, l = t & 63;
  const int wr = w >> 1, wc = w & 1;

  f32x4 acc[4][4] = {};

  const f16* Ap = A + (size_t)(bm + (t >> 2)) * K + (t & 3) * 8;
  const f16* Bp = B + (size_t)(bn + (t >> 2)) * K + (t & 3) * 8;
  f16* lA = &As[t * 8];
  f16* lB = &Bs[t * 8];

  const int fr = l & 15;
  const int kg = l >> 4;

  for (int k0 = 0; k0 < K; k0 += 32) {
    __syncthreads();
    async_copy16(Ap + k0,          lA);
    async_copy16(Ap + 64 * K + k0, lA + 2048);
    async_copy16(Bp + k0,          lB);
    async_copy16(Bp + 64 * K + k0, lB + 2048);
    __syncthreads();

    half8 a[4], b[4];
#pragma unroll
    for (int m = 0; m < 4; ++m)
      a[m] = *(const half8*)&As[(wr * 64 + m * 16 + fr) * 32 + kg * 8];
#pragma unroll
    for (int n = 0; n < 4; ++n)
      b[n] = *(const half8*)&Bs[(wc * 64 + n * 16 + fr) * 32 + kg * 8];
#pragma unroll
    for (int m = 0; m < 4; ++m)
#pragma unroll
      for (int n = 0; n < 4; ++n)
        acc[m][n] = MFMA16(a[m], b[n], acc[m][n]);
  }

  const int r0 = (l >> 4) * 4;
#pragma unroll
  for (int n = 0; n < 4; ++n) {
    int col = bn + wc * 64 + n * 16 + fr;
    float bv = bias[col];
#pragma unroll
    for (int m = 0; m < 4; ++m) {
      int row = bm + wr * 64 + m * 16 + r0;
#pragma unroll
      for (int r = 0; r < 4; ++r)
        C[(size_t)(row + r) * ldc + col] = acc[m][n][r] + bv;
    }
  }
}

// ---------------------------------------------------------------------------
// RoPE + precision-split + V transpose.
// Block = 64 positions. Outputs:
//   qh/ql [4096][768] f16 (hi/lo of roped q, head-major)
//   kh/kl [4096][96]  f16 (hi/lo of roped k)
//   vT    [96][4096]  f16 (transposed v)
// ---------------------------------------------------------------------------
__global__ __launch_bounds__(256) void rope2_kernel(const float* __restrict__ qkv,
                                                    f16* __restrict__ qh,
                                                    f16* __restrict__ ql,
                                                    f16* __restrict__ kh,
                                                    f16* __restrict__ kl,
                                                    f16* __restrict__ vT) {
  __shared__ float cs[64 * 48], sn[64 * 48];
  __shared__ f16 vtile[96 * 64];
  const int t  = threadIdx.x;
  const int i0 = blockIdx.x * 64;

  // pass A: sin/cos table + k rope (64 pos x 48 freqs)
  for (int it = 0; it < 12; ++it) {
    int idx = t + 256 * it;
    int p = idx / 48, f = idx - p * 48;
    float theta = powf(10000.f, -(float)(2 * f) / 96.f);
    float s, c;
    sincosf((float)(i0 + p) * theta, &s, &c);
    cs[p * 48 + f] = c; sn[p * 48 + f] = s;
    const float* row = qkv + (size_t)(i0 + p) * NPAD;
    float e = row[2 * f], o = row[2 * f + 1];
    float re = e * c - o * s, ro = e * s + o * c;
    f16 he = (f16)re, ho = (f16)ro;
    f16x2 hv; hv[0] = he; hv[1] = ho;
    f16x2 lv; lv[0] = (f16)(re - (float)he); lv[1] = (f16)(ro - (float)ho);
    *(f16x2*)(kh + (size_t)(i0 + p) * QD + 2 * f) = hv;
    *(f16x2*)(kl + (size_t)(i0 + p) * QD + 2 * f) = lv;
  }
  // pass V: fill transpose tile (64 pos x 96 dims)
  for (int it = 0; it < 6; ++it) {
    int c = t + 256 * it;
    int p = c / 24, seg = c - p * 24;
    f32x4 v = *(const f32x4*)(qkv + (size_t)(i0 + p) * NPAD + QD + seg * 4);
    vtile[(seg * 4 + 0) * 64 + p] = (f16)v[0];
    vtile[(seg * 4 + 1) * 64 + p] = (f16)v[1];
    vtile[(seg * 4 + 2) * 64 + p] = (f16)v[2];
    vtile[(seg * 4 + 3) * 64 + p] = (f16)v[3];
  }
  __syncthreads();
  // pass B: q rope (64 pos x 8 heads x 48 freqs)
  for (int it = 0; it < 96; ++it) {
    int idx = t + 256 * it;
    int p = idx / 384, rem = idx - p * 384;
    int h = rem / 48, f = rem - h * 48;
    const float* row = qkv + (size_t)(i0 + p) * NPAD + 2 * QD + h * QD;
    float e = row[2 * f], o = row[2 * f + 1];
    float c = cs[p * 48 + f], s = sn[p * 48 + f];
    float re = e * c - o * s, ro = e * s + o * c;
    f16 he = (f16)re, ho = (f16)ro;
    f16x2 hv; hv[0] = he; hv[1] = ho;
    f16x2 lv; lv[0] = (f16)(re - (float)he); lv[1] = (f16)(ro - (float)ho);
    *(f16x2*)(qh + (size_t)(i0 + p) * DM + h * QD + 2 * f) = hv;
    *(f16x2*)(ql + (size_t)(i0 + p) * DM + h * QD + 2 * f) = lv;
  }
  // pass W: write vT rows (96 x 64 halves, coalesced)
  for (int it = 0; it < 3; ++it) {
    int c = t + 256 * it;
    int d = c >> 3, seg = c & 7;
    *(half8*)(vT + (size_t)d * 4096 + i0 + seg * 8) = *(half8*)(vtile + d * 64 + seg * 8);
  }
}

// ---------------------------------------------------------------------------
// MFMA windowed attention. Block = 64-query tile x 2 heads, 4 waves.
// Wave = 1 head x 32 queries x 192 keys. Split-f16 QK^T (3 MFMAs) for
// fp32-grade scores; single-pass masked softmax in registers; PV via
// LDS round-trip of P and LDS-staged vT tile.
// ---------------------------------------------------------------------------
__global__ __launch_bounds__(256, 2) void attn2_kernel(const f16* __restrict__ qh,
                                                       const f16* __restrict__ ql,
                                                       const f16* __restrict__ kh,
                                                       const f16* __restrict__ kl,
                                                       const f16* __restrict__ vT,
                                                       f16* __restrict__ aout) {
  __shared__ f16 kbuf[192 * 104];      // K_hi tile [192][104]; later vT tile [96][200]
  __shared__ f16 pbuf[4][32 * 40];     // per-wave P chunk [32][40]
  const int t  = threadIdx.x, w = t >> 6, l = t & 63;
  const int fr = l & 15, kg = l >> 4;
  const int i0 = blockIdx.x * 64;      // query tile start
  const int h  = blockIdx.y * 2 + (w >> 1);
  const int q0 = (w & 1) * 32;         // query half within tile
  const int jbase = i0 - 128;          // key loc 0 <-> absolute j

  // ---- stage K_hi tile (192 rows x 96 halves -> padded 104)
  for (int it = 0; it < 9; ++it) {
    int c = t + 256 * it;
    int row = c / 12, seg = c - row * 12;
    int jabs = jbase + row; if (jabs < 0) jabs = 0;
    *(half8*)(kbuf + row * 104 + seg * 8) =
        *(const half8*)(kh + (size_t)jabs * QD + seg * 8);
  }

  // ---- Q fragments from global (scattered 16B, L2-hot)
  half8 a_h[2][3], a_l[2][3];
#pragma unroll
  for (int m = 0; m < 2; ++m) {
    size_t qoff = (size_t)(i0 + q0 + m * 16 + fr) * DM + h * QD;
#pragma unroll
    for (int kc = 0; kc < 3; ++kc) {
      a_h[m][kc] = *(const half8*)(qh + qoff + kc * 32 + kg * 8);
      a_l[m][kc] = *(const half8*)(ql + qoff + kc * 32 + kg * 8);
    }
  }
  __syncthreads();

  // ---- S = Q K^T (split precision: hi*hi + lo*hi + hi*lo)
  f32x4 s[2][12];
#pragma unroll
  for (int m = 0; m < 2; ++m)
#pragma unroll
    for (int n = 0; n < 12; ++n)
      s[m][n] = (f32x4){0.f, 0.f, 0.f, 0.f};

#pragma unroll
  for (int n = 0; n < 12; ++n) {
    int krow = n * 16 + fr;
    int jabs = jbase + krow; if (jabs < 0) jabs = 0;
#pragma unroll
    for (int kc = 0; kc < 3; ++kc) {
      half8 b_h = *(const half8*)(kbuf + krow * 104 + kc * 32 + kg * 8);
      half8 b_l = *(const half8*)(kl + (size_t)jabs * QD + kc * 32 + kg * 8);
      s[0][n] = MFMA16(a_h[0][kc], b_h, s[0][n]);
      s[1][n] = MFMA16(a_h[1][kc], b_h, s[1][n]);
      s[0][n] = MFMA16(a_l[0][kc], b_h, s[0][n]);
      s[1][n] = MFMA16(a_l[1][kc], b_h, s[1][n]);
      s[0][n] = MFMA16(a_h[0][kc], b_l, s[0][n]);
      s[1][n] = MFMA16(a_h[1][kc], b_l, s[1][n]);
    }
  }

  // ---- mask + scale + softmax (rows live in (kg, reg); cols in (fr, n))
  const int jmin = (i0 < 128) ? (128 - i0) : 0;
  const float scale = 9.79795897113271f;   // sqrt(96)
  float mx[2][4], sm[2][4], inv[2][4];
#pragma unroll
  for (int m = 0; m < 2; ++m)
#pragma unroll
    for (int r = 0; r < 4; ++r) mx[m][r] = -1e30f;

#pragma unroll
  for (int m = 0; m < 2; ++m)
#pragma unroll
    for (int n = 0; n < 12; ++n) {
      int jloc = n * 16 + fr;
#pragma unroll
      for (int r = 0; r < 4; ++r) {
        int iloc = q0 + m * 16 + kg * 4 + r;
        bool valid = (jloc > iloc) && (jloc <= iloc + 128) && (jloc >= jmin);
        float v = valid ? s[m][n][r] * scale : -1e30f;
        s[m][n][r] = v;
        mx[m][r] = fmaxf(mx[m][r], v);
      }
    }
#pragma unroll
  for (int m = 0; m < 2; ++m)
#pragma unroll
    for (int r = 0; r < 4; ++r) {
      float v = mx[m][r];
      v = fmaxf(v, __shfl_xor(v, 1));
      v = fmaxf(v, __shfl_xor(v, 2));
      v = fmaxf(v, __shfl_xor(v, 4));
      v = fmaxf(v, __shfl_xor(v, 8));
      mx[m][r] = v;
      sm[m][r] = 0.f;
    }
#pragma unroll
  for (int m = 0; m < 2; ++m)
#pragma unroll
    for (int n = 0; n < 12; ++n)
#pragma unroll
      for (int r = 0; r < 4; ++r) {
        float p = __expf(s[m][n][r] - mx[m][r]);
        s[m][n][r] = p;
        sm[m][r] += p;
      }
#pragma unroll
  for (int m = 0; m < 2; ++m)
#pragma unroll
    for (int r = 0; r < 4; ++r) {
      float v = sm[m][r];
      v += __shfl_xor(v, 1);
      v += __shfl_xor(v, 2);
      v += __shfl_xor(v, 4);
      v += __shfl_xor(v, 8);
      inv[m][r] = 1.f / v;
    }

  // ---- restage: vT tile (96 rows x 192 halves -> padded 200) over kbuf
  __syncthreads();
  for (int it = 0; it < 9; ++it) {
    int c = t + 256 * it;
    int row = c / 24, seg = c - row * 24;
    int col0 = jbase + seg * 8; if (col0 < 0) col0 = 0;
    *(half8*)(kbuf + row * 200 + seg * 8) =
        *(const half8*)(vT + (size_t)row * 4096 + col0);
  }
  __syncthreads();

  // ---- PV: 6 key-chunks of 32; P round-trips per-wave LDS into A-layout
  f16* pw = pbuf[w];
  f32x4 o[2][6];
#pragma unroll
  for (int m = 0; m < 2; ++m)
#pragma unroll
    for (int dn = 0; dn < 6; ++dn)
      o[m][dn] = (f32x4){0.f, 0.f, 0.f, 0.f};

#pragma unroll
  for (int c6 = 0; c6 < 6; ++c6) {
#pragma unroll
    for (int m = 0; m < 2; ++m)
#pragma unroll
      for (int nn = 0; nn < 2; ++nn)
#pragma unroll
        for (int r = 0; r < 4; ++r)
          pw[(m * 16 + kg * 4 + r) * 40 + nn * 16 + fr] = (f16)s[m][2 * c6 + nn][r];
    __syncthreads();
    half8 ap0 = *(half8*)(pw + fr * 40 + kg * 8);
    half8 ap1 = *(half8*)(pw + (16 + fr) * 40 + kg * 8);
#pragma unroll
    for (int dn = 0; dn < 6; ++dn) {
      half8 bv = *(half8*)(kbuf + (dn * 16 + fr) * 200 + c6 * 32 + kg * 8);
      o[0][dn] = MFMA16(ap0, bv, o[0][dn]);
      o[1][dn] = MFMA16(ap1, bv, o[1][dn]);
    }
    __syncthreads();
  }

  // ---- epilogue: normalize + store aout f16 [4096][768]
#pragma unroll
  for (int m = 0; m < 2; ++m)
#pragma unroll
    for (int dn = 0; dn < 6; ++dn) {
      int col = h * QD + dn * 16 + fr;
#pragma unroll
      for (int r = 0; r < 4; ++r) {
        int row = i0 + q0 + m * 16 + kg * 4 + r;
        aout[(size_t)row * DM + col] = (f16)(o[m][dn][r] * inv[m][r]);
      }
    }
}

// ---------------------------------------------------------------------------
extern "C" void kernel_launch(void* const* d_in, const int* in_sizes, int n_in,
                              void* d_out, int out_size, void* d_ws, size_t ws_size,
                              hipStream_t stream) {
  const float* x    = (const float*)d_in[0];
  const float* Wqkv = (const float*)d_in[1];
  const float* bqkv = (const float*)d_in[2];
  const float* Wout = (const float*)d_in[3];
  const float* bout = (const float*)d_in[4];
  float* out = (float*)d_out;

  char* ws = (char*)d_ws;
  f16*   xh   = (f16*)(ws);                    // 6291456   (x f16; reused as qh)
  f16*   w1h  = (f16*)(ws + 6291456);          // 1572864
  f16*   w2h  = (f16*)(ws + 7864320);          // 1179648
  float* b1p  = (float*)(ws + 9043968);        // 4096
  float* qkv  = (float*)(ws + 9048064);        // 16777216  (f32; reused as aout)
  f16*   ql   = (f16*)(ws + 25825280);         // 6291456
  f16*   khh  = (f16*)(ws + 32116736);         // 786432
  f16*   khl  = (f16*)(ws + 32903168);         // 786432
  f16*   vT   = (f16*)(ws + 33689600);         // 786432    -> total 34476032
  f16*   qhh  = xh;                            // alias: x f16 dead after gemm1
  f16*   aout = (f16*)qkv;                     // alias: qkv dead after rope2

  cast_x_kernel<<<dim3(3072), dim3(256), 0, stream>>>(x, xh);
  prep_w_kernel<<<dim3(1348), dim3(256), 0, stream>>>(Wqkv, bqkv, Wout, w1h, w2h, b1p);
  gemm_f16_tn<<<dim3(8, 32), dim3(256), 0, stream>>>(xh, w1h, b1p, qkv, 768, 1024);
  rope2_kernel<<<dim3(64), dim3(256), 0, stream>>>(qkv, qhh, ql, khh, khl, vT);
  attn2_kernel<<<dim3(64, 4), dim3(256), 0, stream>>>(qhh, ql, khh, khl, vT, aout);
  gemm_f16_tn<<<dim3(6, 32), dim3(256), 0, stream>>>(aout, w2h, bout, out, 768, 768);
}

// Round 3
// 76.177 us; speedup vs baseline: 4.7207x; 1.4845x over previous
//
#include <hip/hip_runtime.h>

typedef _Float16 f16;
typedef _Float16 half8 __attribute__((ext_vector_type(8)));
typedef _Float16 f16x2 __attribute__((ext_vector_type(2)));
typedef _Float16 f16x4 __attribute__((ext_vector_type(4)));
typedef float    f32x4 __attribute__((ext_vector_type(4)));

#define DM    768
#define QD    96
#define NPAD  1024
#define MFMA16(a,b,c) __builtin_amdgcn_mfma_f32_16x16x32_f16(a, b, c, 0, 0, 0)

// ---------------------------------------------------------------------------
__device__ __forceinline__ void async_copy16(const f16* g, f16* l) {
  __builtin_amdgcn_global_load_lds((const __attribute__((address_space(1))) void*)g,
                                   (__attribute__((address_space(3))) void*)l,
                                   16, 0, 0);
}

// ---------------------------------------------------------------------------
// merged: cast x -> f16 (blocks < 3072), cast/pad weights (blocks >= 3072)
// ---------------------------------------------------------------------------
__global__ __launch_bounds__(256) void prep_kernel(const float* __restrict__ x,
                                                   const float* __restrict__ Wqkv,
                                                   const float* __restrict__ bqkv,
                                                   const float* __restrict__ Wout,
                                                   f16* __restrict__ xh,
                                                   f16* __restrict__ w1h,
                                                   f16* __restrict__ w2h,
                                                   float* __restrict__ b1p) {
  const int NW1 = 1024 * 768 / 4;
  const int NW2 = 768 * 768 / 4;
  int b = blockIdx.x;
  if (b < 3072) {                       // x cast: 4096*768/4 items
    int idx = b * 256 + threadIdx.x;
    f32x4 v = ((const f32x4*)x)[idx];
    f16x4 o;
    o[0] = (f16)v[0]; o[1] = (f16)v[1]; o[2] = (f16)v[2]; o[3] = (f16)v[3];
    ((f16x4*)xh)[idx] = o;
    return;
  }
  int idx = (b - 3072) * 256 + threadIdx.x;
  if (idx < NW1) {
    int r = idx / 192;
    f16x4 o;
    if (r < 960) {
      f32x4 v = ((const f32x4*)Wqkv)[idx];
      o[0] = (f16)v[0]; o[1] = (f16)v[1]; o[2] = (f16)v[2]; o[3] = (f16)v[3];
    } else {
      o[0] = (f16)0.f; o[1] = (f16)0.f; o[2] = (f16)0.f; o[3] = (f16)0.f;
    }
    ((f16x4*)w1h)[idx] = o;
  } else if (idx < NW1 + NW2) {
    int j = idx - NW1;
    f32x4 v = ((const f32x4*)Wout)[j];
    f16x4 o;
    o[0] = (f16)v[0]; o[1] = (f16)v[1]; o[2] = (f16)v[2]; o[3] = (f16)v[3];
    ((f16x4*)w2h)[j] = o;
  } else {
    int j = idx - (NW1 + NW2);
    b1p[j] = (j < 960) ? bqkv[j] : 0.f;
  }
}

// ---------------------------------------------------------------------------
// GEMM: C[M x ldc](f32) = A[M x K](f16) * B[N x K](f16)^T + bias
// 64x128 tile, BK=32, 4 waves (each 64x32 out), mfma 16x16x32, gl_lds staging.
// grid = (N/128, M/64). Requires M%64==0, N%128==0, K%32==0.
// ---------------------------------------------------------------------------
__global__ __launch_bounds__(256) void gemm_f16_tn(const f16* __restrict__ A,
                                                   const f16* __restrict__ B,
                                                   const float* __restrict__ bias,
                                                   float* __restrict__ C,
                                                   int K, int ldc) {
  __shared__ f16 As[64 * 32];
  __shared__ f16 Bs[128 * 32];
  const int t  = threadIdx.x;
  const int bm = blockIdx.y * 64;
  const int bn = blockIdx.x * 128;
  const int w  = t >> 6, l = t & 63;

  f32x4 acc[4][2] = {};

  const f16* Ap = A + (size_t)(bm + (t >> 2)) * K + (t & 3) * 8;
  const f16* Bp = B + (size_t)(bn + (t >> 2)) * K + (t & 3) * 8;
  f16* lA = &As[t * 8];
  f16* lB = &Bs[t * 8];

  const int fr = l & 15;
  const int kg = l >> 4;

  for (int k0 = 0; k0 < K; k0 += 32) {
    __syncthreads();
    async_copy16(Ap + k0,          lA);
    async_copy16(Bp + k0,          lB);
    async_copy16(Bp + 64 * K + k0, lB + 2048);
    __syncthreads();

    half8 a[4], b[2];
#pragma unroll
    for (int m = 0; m < 4; ++m)
      a[m] = *(const half8*)&As[(m * 16 + fr) * 32 + kg * 8];
#pragma unroll
    for (int n = 0; n < 2; ++n)
      b[n] = *(const half8*)&Bs[(w * 32 + n * 16 + fr) * 32 + kg * 8];
#pragma unroll
    for (int m = 0; m < 4; ++m)
#pragma unroll
      for (int n = 0; n < 2; ++n)
        acc[m][n] = MFMA16(a[m], b[n], acc[m][n]);
  }

  const int r0 = (l >> 4) * 4;
#pragma unroll
  for (int n = 0; n < 2; ++n) {
    int col = bn + w * 32 + n * 16 + fr;
    float bv = bias[col];
#pragma unroll
    for (int m = 0; m < 4; ++m) {
      int row = bm + m * 16 + r0;
#pragma unroll
      for (int r = 0; r < 4; ++r)
        C[(size_t)(row + r) * ldc + col] = acc[m][n][r] + bv;
    }
  }
}

// ---------------------------------------------------------------------------
// RoPE + precision-split + V transpose. Block = 16 positions, grid 256.
// All index math pow2 (freqs padded 48->64 with lane guard).
// ---------------------------------------------------------------------------
#define RPOS 16
__global__ __launch_bounds__(256) void rope2_kernel(const float* __restrict__ qkv,
                                                    f16* __restrict__ qh,
                                                    f16* __restrict__ ql,
                                                    f16* __restrict__ kh,
                                                    f16* __restrict__ kl,
                                                    f16* __restrict__ vT) {
  __shared__ float cs[RPOS * 48], sn[RPOS * 48];
  __shared__ f16 vtile[96 * 17];            // [d][p], stride 17 vs 16 (bank pad)
  const int t  = threadIdx.x;
  const int i0 = blockIdx.x * RPOS;

  // Phase A: sincos table + k rope. idx: p=idx>>6, f=idx&63 (f<48)
#pragma unroll
  for (int it = 0; it < RPOS * 64 / 256; ++it) {
    int idx = t + 256 * it;
    int p = idx >> 6, f = idx & 63;
    if (f < 48) {
      float theta = exp2f((float)f * -0.27682734f);   // 10000^(-2f/96)
      float s, c;
      sincosf((float)(i0 + p) * theta, &s, &c);
      cs[p * 48 + f] = c; sn[p * 48 + f] = s;
      const float* row = qkv + (size_t)(i0 + p) * NPAD;
      float e = row[2 * f], o = row[2 * f + 1];
      float re = e * c - o * s, ro = e * s + o * c;
      f16 he = (f16)re, ho = (f16)ro;
      f16x2 hv; hv[0] = he; hv[1] = ho;
      f16x2 lv; lv[0] = (f16)(re - (float)he); lv[1] = (f16)(ro - (float)ho);
      *(f16x2*)(kh + (size_t)(i0 + p) * QD + 2 * f) = hv;
      *(f16x2*)(kl + (size_t)(i0 + p) * QD + 2 * f) = lv;
    }
  }
  // Phase V: v into transpose tile. idx: p=idx>>5, c=idx&31 (c<24, 4 floats)
#pragma unroll
  for (int it = 0; it < RPOS * 32 / 256; ++it) {
    int idx = t + 256 * it;
    int p = idx >> 5, c = idx & 31;
    if (c < 24) {
      f32x4 v = *(const f32x4*)(qkv + (size_t)(i0 + p) * NPAD + QD + c * 4);
#pragma unroll
      for (int j = 0; j < 4; ++j)
        vtile[(c * 4 + j) * 17 + p] = (f16)v[j];
    }
  }
  __syncthreads();
  // Phase B: q rope. idx: p=idx>>9, h=(idx>>6)&7, f=idx&63 (f<48)
#pragma unroll
  for (int it = 0; it < RPOS * 8 * 64 / 256; ++it) {
    int idx = t + 256 * it;
    int p = idx >> 9, h = (idx >> 6) & 7, f = idx & 63;
    if (f < 48) {
      const float* row = qkv + (size_t)(i0 + p) * NPAD + 2 * QD + h * QD;
      float e = row[2 * f], o = row[2 * f + 1];
      float c = cs[p * 48 + f], s = sn[p * 48 + f];
      float re = e * c - o * s, ro = e * s + o * c;
      f16 he = (f16)re, ho = (f16)ro;
      f16x2 hv; hv[0] = he; hv[1] = ho;
      f16x2 lv; lv[0] = (f16)(re - (float)he); lv[1] = (f16)(ro - (float)ho);
      *(f16x2*)(qh + (size_t)(i0 + p) * DM + h * QD + 2 * f) = hv;
      *(f16x2*)(ql + (size_t)(i0 + p) * DM + h * QD + 2 * f) = lv;
    }
  }
  // Phase W: write vT rows. idx<192: d=idx>>1, half=idx&1 (8 halves each)
  {
    int d = t >> 1, half = t & 1;
    if (t < 192) {
      half8 o;
#pragma unroll
      for (int j = 0; j < 8; ++j) o[j] = vtile[d * 17 + half * 8 + j];
      *(half8*)(vT + (size_t)d * 4096 + i0 + half * 8) = o;
    }
  }
}

// ---------------------------------------------------------------------------
// MFMA windowed attention (unchanged from round 2).
// ---------------------------------------------------------------------------
__global__ __launch_bounds__(256, 2) void attn2_kernel(const f16* __restrict__ qh,
                                                       const f16* __restrict__ ql,
                                                       const f16* __restrict__ kh,
                                                       const f16* __restrict__ kl,
                                                       const f16* __restrict__ vT,
                                                       f16* __restrict__ aout) {
  __shared__ f16 kbuf[192 * 104];
  __shared__ f16 pbuf[4][32 * 40];
  const int t  = threadIdx.x, w = t >> 6, l = t & 63;
  const int fr = l & 15, kg = l >> 4;
  const int i0 = blockIdx.x * 64;
  const int h  = blockIdx.y * 2 + (w >> 1);
  const int q0 = (w & 1) * 32;
  const int jbase = i0 - 128;

  for (int it = 0; it < 9; ++it) {
    int c = t + 256 * it;
    int row = c / 12, seg = c - row * 12;
    int jabs = jbase + row; if (jabs < 0) jabs = 0;
    *(half8*)(kbuf + row * 104 + seg * 8) =
        *(const half8*)(kh + (size_t)jabs * QD + seg * 8);
  }

  half8 a_h[2][3], a_l[2][3];
#pragma unroll
  for (int m = 0; m < 2; ++m) {
    size_t qoff = (size_t)(i0 + q0 + m * 16 + fr) * DM + h * QD;
#pragma unroll
    for (int kc = 0; kc < 3; ++kc) {
      a_h[m][kc] = *(const half8*)(qh + qoff + kc * 32 + kg * 8);
      a_l[m][kc] = *(const half8*)(ql + qoff + kc * 32 + kg * 8);
    }
  }
  __syncthreads();

  f32x4 s[2][12];
#pragma unroll
  for (int m = 0; m < 2; ++m)
#pragma unroll
    for (int n = 0; n < 12; ++n)
      s[m][n] = (f32x4){0.f, 0.f, 0.f, 0.f};

#pragma unroll
  for (int n = 0; n < 12; ++n) {
    int krow = n * 16 + fr;
    int jabs = jbase + krow; if (jabs < 0) jabs = 0;
#pragma unroll
    for (int kc = 0; kc < 3; ++kc) {
      half8 b_h = *(const half8*)(kbuf + krow * 104 + kc * 32 + kg * 8);
      half8 b_l = *(const half8*)(kl + (size_t)jabs * QD + kc * 32 + kg * 8);
      s[0][n] = MFMA16(a_h[0][kc], b_h, s[0][n]);
      s[1][n] = MFMA16(a_h[1][kc], b_h, s[1][n]);
      s[0][n] = MFMA16(a_l[0][kc], b_h, s[0][n]);
      s[1][n] = MFMA16(a_l[1][kc], b_h, s[1][n]);
      s[0][n] = MFMA16(a_h[0][kc], b_l, s[0][n]);
      s[1][n] = MFMA16(a_h[1][kc], b_l, s[1][n]);
    }
  }

  const int jmin = (i0 < 128) ? (128 - i0) : 0;
  const float scale = 9.79795897113271f;
  float mx[2][4], sm[2][4], inv[2][4];
#pragma unroll
  for (int m = 0; m < 2; ++m)
#pragma unroll
    for (int r = 0; r < 4; ++r) mx[m][r] = -1e30f;

#pragma unroll
  for (int m = 0; m < 2; ++m)
#pragma unroll
    for (int n = 0; n < 12; ++n) {
      int jloc = n * 16 + fr;
#pragma unroll
      for (int r = 0; r < 4; ++r) {
        int iloc = q0 + m * 16 + kg * 4 + r;
        bool valid = (jloc > iloc) && (jloc <= iloc + 128) && (jloc >= jmin);
        float v = valid ? s[m][n][r] * scale : -1e30f;
        s[m][n][r] = v;
        mx[m][r] = fmaxf(mx[m][r], v);
      }
    }
#pragma unroll
  for (int m = 0; m < 2; ++m)
#pragma unroll
    for (int r = 0; r < 4; ++r) {
      float v = mx[m][r];
      v = fmaxf(v, __shfl_xor(v, 1));
      v = fmaxf(v, __shfl_xor(v, 2));
      v = fmaxf(v, __shfl_xor(v, 4));
      v = fmaxf(v, __shfl_xor(v, 8));
      mx[m][r] = v;
      sm[m][r] = 0.f;
    }
#pragma unroll
  for (int m = 0; m < 2; ++m)
#pragma unroll
    for (int n = 0; n < 12; ++n)
#pragma unroll
      for (int r = 0; r < 4; ++r) {
        float p = __expf(s[m][n][r] - mx[m][r]);
        s[m][n][r] = p;
        sm[m][r] += p;
      }
#pragma unroll
  for (int m = 0; m < 2; ++m)
#pragma unroll
    for (int r = 0; r < 4; ++r) {
      float v = sm[m][r];
      v += __shfl_xor(v, 1);
      v += __shfl_xor(v, 2);
      v += __shfl_xor(v, 4);
      v += __shfl_xor(v, 8);
      inv[m][r] = 1.f / v;
    }

  __syncthreads();
  for (int it = 0; it < 9; ++it) {
    int c = t + 256 * it;
    int row = c / 24, seg = c - row * 24;
    int col0 = jbase + seg * 8; if (col0 < 0) col0 = 0;
    *(half8*)(kbuf + row * 200 + seg * 8) =
        *(const half8*)(vT + (size_t)row * 4096 + col0);
  }
  __syncthreads();

  f16* pw = pbuf[w];
  f32x4 o[2][6];
#pragma unroll
  for (int m = 0; m < 2; ++m)
#pragma unroll
    for (int dn = 0; dn < 6; ++dn)
      o[m][dn] = (f32x4){0.f, 0.f, 0.f, 0.f};

#pragma unroll
  for (int c6 = 0; c6 < 6; ++c6) {
#pragma unroll
    for (int m = 0; m < 2; ++m)
#pragma unroll
      for (int nn = 0; nn < 2; ++nn)
#pragma unroll
        for (int r = 0; r < 4; ++r)
          pw[(m * 16 + kg * 4 + r) * 40 + nn * 16 + fr] = (f16)s[m][2 * c6 + nn][r];
    __syncthreads();
    half8 ap0 = *(half8*)(pw + fr * 40 + kg * 8);
    half8 ap1 = *(half8*)(pw + (16 + fr) * 40 + kg * 8);
#pragma unroll
    for (int dn = 0; dn < 6; ++dn) {
      half8 bv = *(half8*)(kbuf + (dn * 16 + fr) * 200 + c6 * 32 + kg * 8);
      o[0][dn] = MFMA16(ap0, bv, o[0][dn]);
      o[1][dn] = MFMA16(ap1, bv, o[1][dn]);
    }
    __syncthreads();
  }

#pragma unroll
  for (int m = 0; m < 2; ++m)
#pragma unroll
    for (int dn = 0; dn < 6; ++dn) {
      int col = h * QD + dn * 16 + fr;
#pragma unroll
      for (int r = 0; r < 4; ++r) {
        int row = i0 + q0 + m * 16 + kg * 4 + r;
        aout[(size_t)row * DM + col] = (f16)(o[m][dn][r] * inv[m][r]);
      }
    }
}

// ---------------------------------------------------------------------------
extern "C" void kernel_launch(void* const* d_in, const int* in_sizes, int n_in,
                              void* d_out, int out_size, void* d_ws, size_t ws_size,
                              hipStream_t stream) {
  const float* x    = (const float*)d_in[0];
  const float* Wqkv = (const float*)d_in[1];
  const float* bqkv = (const float*)d_in[2];
  const float* Wout = (const float*)d_in[3];
  const float* bout = (const float*)d_in[4];
  float* out = (float*)d_out;

  char* ws = (char*)d_ws;
  f16*   xh   = (f16*)(ws);                    // 6291456 (x f16; reused as qh)
  f16*   w1h  = (f16*)(ws + 6291456);          // 1572864
  f16*   w2h  = (f16*)(ws + 7864320);          // 1179648
  float* b1p  = (float*)(ws + 9043968);        // 4096
  float* qkv  = (float*)(ws + 9048064);        // 16777216 (f32; reused as aout)
  f16*   ql   = (f16*)(ws + 25825280);         // 6291456
  f16*   khh  = (f16*)(ws + 32116736);         // 786432
  f16*   khl  = (f16*)(ws + 32903168);         // 786432
  f16*   vT   = (f16*)(ws + 33689600);         // 786432  -> total 34476032
  f16*   qhh  = xh;
  f16*   aout = (f16*)qkv;

  prep_kernel<<<dim3(4420), dim3(256), 0, stream>>>(x, Wqkv, bqkv, Wout, xh, w1h, w2h, b1p);
  gemm_f16_tn<<<dim3(8, 64), dim3(256), 0, stream>>>(xh, w1h, b1p, qkv, 768, 1024);
  rope2_kernel<<<dim3(256), dim3(256), 0, stream>>>(qkv, qhh, ql, khh, khl, vT);
  attn2_kernel<<<dim3(64, 4), dim3(256), 0, stream>>>(qhh, ql, khh, khl, vT, aout);
  gemm_f16_tn<<<dim3(6, 64), dim3(256), 0, stream>>>(aout, w2h, bout, out, 768, 768);
}

// Round 4
// 74.998 us; speedup vs baseline: 4.7949x; 1.0157x over previous
//
#include <hip/hip_runtime.h>

typedef _Float16 f16;
typedef _Float16 half8 __attribute__((ext_vector_type(8)));
typedef _Float16 f16x2 __attribute__((ext_vector_type(2)));
typedef _Float16 f16x4 __attribute__((ext_vector_type(4)));
typedef float    f32x4 __attribute__((ext_vector_type(4)));

#define DM    768
#define QD    96
#define MFMA16(a,b,c) __builtin_amdgcn_mfma_f32_16x16x32_f16(a, b, c, 0, 0, 0)

// ---------------------------------------------------------------------------
__device__ __forceinline__ void async_copy16(const f16* g, f16* l) {
  __builtin_amdgcn_global_load_lds((const __attribute__((address_space(1))) void*)g,
                                   (__attribute__((address_space(3))) void*)l,
                                   16, 0, 0);
}

// ---------------------------------------------------------------------------
// merged prep: x cast (b<3072), weight cast/pad (b<4420), sincos table (rest)
// ---------------------------------------------------------------------------
__global__ __launch_bounds__(256) void prep_kernel(const float* __restrict__ x,
                                                   const float* __restrict__ Wqkv,
                                                   const float* __restrict__ bqkv,
                                                   const float* __restrict__ Wout,
                                                   f16* __restrict__ xh,
                                                   f16* __restrict__ w1h,
                                                   f16* __restrict__ w2h,
                                                   float* __restrict__ b1p,
                                                   float* __restrict__ ctab,
                                                   float* __restrict__ stab) {
  const int NW1 = 1024 * 768 / 4;
  const int NW2 = 768 * 768 / 4;
  int b = blockIdx.x;
  if (b < 3072) {                       // x cast: 4096*768/4 items
    int idx = b * 256 + threadIdx.x;
    f32x4 v = ((const f32x4*)x)[idx];
    f16x4 o;
    o[0] = (f16)v[0]; o[1] = (f16)v[1]; o[2] = (f16)v[2]; o[3] = (f16)v[3];
    ((f16x4*)xh)[idx] = o;
    return;
  }
  if (b < 4420) {                       // weights + bias
    int idx = (b - 3072) * 256 + threadIdx.x;
    if (idx < NW1) {
      int r = idx / 192;
      f16x4 o;
      if (r < 960) {
        f32x4 v = ((const f32x4*)Wqkv)[idx];
        o[0] = (f16)v[0]; o[1] = (f16)v[1]; o[2] = (f16)v[2]; o[3] = (f16)v[3];
      } else {
        o[0] = (f16)0.f; o[1] = (f16)0.f; o[2] = (f16)0.f; o[3] = (f16)0.f;
      }
      ((f16x4*)w1h)[idx] = o;
    } else if (idx < NW1 + NW2) {
      int j = idx - NW1;
      f32x4 v = ((const f32x4*)Wout)[j];
      f16x4 o;
      o[0] = (f16)v[0]; o[1] = (f16)v[1]; o[2] = (f16)v[2]; o[3] = (f16)v[3];
      ((f16x4*)w2h)[j] = o;
    } else {
      int j = idx - (NW1 + NW2);
      b1p[j] = (j < 960) ? bqkv[j] : 0.f;
    }
    return;
  }
  // sincos table: 4096 pos x 48 freqs (padded loop to 64, pow2 math)
  int idx = (b - 4420) * 256 + threadIdx.x;
  int pos = idx >> 6, f = idx & 63;
  if (f < 48) {
    float theta = exp2f((float)f * -0.27682734f);   // 10000^(-2f/96)
    float s, c;
    sincosf((float)pos * theta, &s, &c);
    ctab[pos * 48 + f] = c;
    stab[pos * 48 + f] = s;
  }
}

// ---------------------------------------------------------------------------
// shared GEMM macros: 64x128 tile, BK=32, 4 waves, double-buffered LDS,
// 2-phase pipeline (STAGE(next) issued before COMPUTE(cur), 1 barrier/step).
// ---------------------------------------------------------------------------
#define GEMM_STAGE(NXT, K0)                                   \
  do {                                                        \
    async_copy16(Ap + (K0),          lA0 + (NXT) * 2048);     \
    async_copy16(Bp + (K0),          lB0 + (NXT) * 4096);     \
    async_copy16(Bp + 64 * K + (K0), lB0 + (NXT) * 4096 + 2048); \
  } while (0)

#define GEMM_COMPUTE(BUF)                                                   \
  do {                                                                      \
    half8 a[4], b[2];                                                       \
    _Pragma("unroll")                                                       \
    for (int m = 0; m < 4; ++m)                                             \
      a[m] = *(const half8*)&As[BUF][(m * 16 + fr) * 32 + kg * 8];          \
    _Pragma("unroll")                                                       \
    for (int n = 0; n < 2; ++n)                                             \
      b[n] = *(const half8*)&Bs[BUF][(w * 32 + n * 16 + fr) * 32 + kg * 8]; \
    _Pragma("unroll")                                                       \
    for (int m = 0; m < 4; ++m)                                             \
      _Pragma("unroll")                                                     \
      for (int n = 0; n < 2; ++n)                                           \
        acc[m][n] = MFMA16(a[m], b[n], acc[m][n]);                          \
  } while (0)

#define GEMM_PROLOGUE_AND_LOOP                                \
  __shared__ f16 As[2][64 * 32];                              \
  __shared__ f16 Bs[2][128 * 32];                             \
  const int t  = threadIdx.x;                                 \
  const int bm = blockIdx.y * 64;                             \
  const int bn = blockIdx.x * 128;                            \
  const int w  = t >> 6, l = t & 63;                          \
  const int fr = l & 15, kg = l >> 4;                         \
  f32x4 acc[4][2] = {};                                       \
  const f16* Ap = A + (size_t)(bm + (t >> 2)) * K + (t & 3) * 8; \
  const f16* Bp = B + (size_t)(bn + (t >> 2)) * K + (t & 3) * 8; \
  f16* lA0 = &As[0][t * 8];                                   \
  f16* lB0 = &Bs[0][t * 8];                                   \
  const int nt = K >> 5; /* must be even */                   \
  GEMM_STAGE(0, 0);                                           \
  __syncthreads();                                            \
  for (int tk = 0; tk < nt; tk += 2) {                        \
    GEMM_STAGE(1, (tk + 1) << 5);                             \
    GEMM_COMPUTE(0);                                          \
    __syncthreads();                                          \
    if (tk + 2 < nt) GEMM_STAGE(0, (tk + 2) << 5);            \
    GEMM_COMPUTE(1);                                          \
    if (tk + 2 < nt) __syncthreads();                         \
  }

// ---------------------------------------------------------------------------
// GEMM2: C[M x ldc](f32) = A * B^T + bias (generic epilogue)
// ---------------------------------------------------------------------------
__global__ __launch_bounds__(256) void gemm_f16_tn(const f16* __restrict__ A,
                                                   const f16* __restrict__ B,
                                                   const float* __restrict__ bias,
                                                   float* __restrict__ C,
                                                   int K, int ldc) {
  GEMM_PROLOGUE_AND_LOOP
  const int r0 = kg * 4;
#pragma unroll
  for (int n = 0; n < 2; ++n) {
    int col = bn + w * 32 + n * 16 + fr;
    float bv = bias[col];
#pragma unroll
    for (int m = 0; m < 4; ++m) {
      int row = bm + m * 16 + r0;
#pragma unroll
      for (int r = 0; r < 4; ++r)
        C[(size_t)(row + r) * ldc + col] = acc[m][n][r] + bv;
    }
  }
}

// ---------------------------------------------------------------------------
// GEMM1 fused: qkv GEMM + bias + RoPE (table) + f16 hi/lo split + V transpose.
// Columns: [0,96)=k -> kh/kl; [96,192)=v -> vT; [192,960)=q -> qh/ql; >=960 pad.
// RoPE pair (2f,2f+1) = adjacent cols = lanes (fr, fr^1): shfl_xor exchange.
// ---------------------------------------------------------------------------
__global__ __launch_bounds__(256) void gemm_qkv_rope(const f16* __restrict__ A,
                                                     const f16* __restrict__ B,
                                                     const float* __restrict__ bias,
                                                     const float* __restrict__ ctab,
                                                     const float* __restrict__ stab,
                                                     f16* __restrict__ qh,
                                                     f16* __restrict__ ql,
                                                     f16* __restrict__ kh,
                                                     f16* __restrict__ kl,
                                                     f16* __restrict__ vT) {
  const int K = 768;
  GEMM_PROLOGUE_AND_LOOP
  const int r0 = kg * 4;
#pragma unroll
  for (int n = 0; n < 2; ++n) {
    int col = bn + w * 32 + n * 16 + fr;
    float bv = bias[col];
    int seg = (col * 683) >> 16;        // col / 96
    int segoff = col - seg * 96;
    int f = segoff >> 1;
    bool odd = col & 1;
#pragma unroll
    for (int m = 0; m < 4; ++m) {
      int row = bm + m * 16 + r0;
#pragma unroll
      for (int r = 0; r < 4; ++r) {
        float v = acc[m][n][r] + bv;
        float p = __shfl_xor(v, 1);     // partner column of the rope pair
        if (seg == 1) {                 // v column
          vT[(size_t)(col - 96) * 4096 + (row + r)] = (f16)v;
        } else if (col < 960) {         // k or q column: rope
          float c = ctab[(row + r) * 48 + f];
          float s = stab[(row + r) * 48 + f];
          float e = odd ? p : v;
          float o = odd ? v : p;
          float res = odd ? (e * s + o * c) : (e * c - o * s);
          f16 hi = (f16)res;
          f16 lo = (f16)(res - (float)hi);
          if (seg == 0) {
            kh[(size_t)(row + r) * QD + col] = hi;
            kl[(size_t)(row + r) * QD + col] = lo;
          } else {
            int qc = col - 192;
            qh[(size_t)(row + r) * DM + qc] = hi;
            ql[(size_t)(row + r) * DM + qc] = lo;
          }
        }
      }
    }
  }
}

// ---------------------------------------------------------------------------
// MFMA windowed attention. Block = 64-query tile x 2 heads, 4 waves.
// Wave = 1 head x 32 queries x 192 keys; chunk pruning (10 of 12 can be live);
// split-f16 QK^T; in-register masked softmax; PV via per-wave LDS round-trip.
// ---------------------------------------------------------------------------
__global__ __launch_bounds__(256, 2) void attn2_kernel(const f16* __restrict__ qh,
                                                       const f16* __restrict__ ql,
                                                       const f16* __restrict__ kh,
                                                       const f16* __restrict__ kl,
                                                       const f16* __restrict__ vT,
                                                       f16* __restrict__ aout) {
  __shared__ f16 kbuf[192 * 104];      // K_hi tile; later vT tile [96][200]
  __shared__ f16 pbuf[4][32 * 40];     // per-wave P chunk (wave-private)
  const int t  = threadIdx.x, w = t >> 6, l = t & 63;
  const int fr = l & 15, kg = l >> 4;
  const int i0 = blockIdx.x * 64;
  const int h  = blockIdx.y * 2 + (w >> 1);
  const int q0 = (w & 1) * 32;
  const int jbase = i0 - 128;
  const int nlo = (w & 1) ? 2 : 0;     // live key-chunks: [nlo, nlo+10)

  // stage K_hi tile (192 x 96 -> padded 104)
  for (int it = 0; it < 9; ++it) {
    int c = t + 256 * it;
    int row = c / 12, seg = c - row * 12;
    int jabs = jbase + row; if (jabs < 0) jabs = 0;
    *(half8*)(kbuf + row * 104 + seg * 8) =
        *(const half8*)(kh + (size_t)jabs * QD + seg * 8);
  }

  half8 a_h[2][3], a_l[2][3];
#pragma unroll
  for (int m = 0; m < 2; ++m) {
    size_t qoff = (size_t)(i0 + q0 + m * 16 + fr) * DM + h * QD;
#pragma unroll
    for (int kc = 0; kc < 3; ++kc) {
      a_h[m][kc] = *(const half8*)(qh + qoff + kc * 32 + kg * 8);
      a_l[m][kc] = *(const half8*)(ql + qoff + kc * 32 + kg * 8);
    }
  }
  __syncthreads();

  // S = Q K^T  (hi*hi + lo*hi + hi*lo)
  f32x4 s[2][12];
#pragma unroll
  for (int m = 0; m < 2; ++m)
#pragma unroll
    for (int n = 0; n < 12; ++n)
      s[m][n] = (f32x4){0.f, 0.f, 0.f, 0.f};

  __builtin_amdgcn_s_setprio(1);
#pragma unroll
  for (int n = 0; n < 12; ++n) {
    if (n < nlo || n >= nlo + 10) continue;
    int krow = n * 16 + fr;
    int jabs = jbase + krow; if (jabs < 0) jabs = 0;
#pragma unroll
    for (int kc = 0; kc < 3; ++kc) {
      half8 b_h = *(const half8*)(kbuf + krow * 104 + kc * 32 + kg * 8);
      half8 b_l = *(const half8*)(kl + (size_t)jabs * QD + kc * 32 + kg * 8);
      s[0][n] = MFMA16(a_h[0][kc], b_h, s[0][n]);
      s[1][n] = MFMA16(a_h[1][kc], b_h, s[1][n]);
      s[0][n] = MFMA16(a_l[0][kc], b_h, s[0][n]);
      s[1][n] = MFMA16(a_l[1][kc], b_h, s[1][n]);
      s[0][n] = MFMA16(a_h[0][kc], b_l, s[0][n]);
      s[1][n] = MFMA16(a_h[1][kc], b_l, s[1][n]);
    }
  }
  __builtin_amdgcn_s_setprio(0);

  // mask + scale + softmax
  const int jmin = (i0 < 128) ? (128 - i0) : 0;
  const float scale = 9.79795897113271f;
  float mx[2][4], sm[2][4], inv[2][4];
#pragma unroll
  for (int m = 0; m < 2; ++m)
#pragma unroll
    for (int r = 0; r < 4; ++r) mx[m][r] = -1e30f;

#pragma unroll
  for (int m = 0; m < 2; ++m)
#pragma unroll
    for (int n = 0; n < 12; ++n) {
      if (n < nlo || n >= nlo + 10) continue;
      int jloc = n * 16 + fr;
#pragma unroll
      for (int r = 0; r < 4; ++r) {
        int iloc = q0 + m * 16 + kg * 4 + r;
        bool valid = (jloc > iloc) && (jloc <= iloc + 128) && (jloc >= jmin);
        float v = valid ? s[m][n][r] * scale : -1e30f;
        s[m][n][r] = v;
        mx[m][r] = fmaxf(mx[m][r], v);
      }
    }
#pragma unroll
  for (int m = 0; m < 2; ++m)
#pragma unroll
    for (int r = 0; r < 4; ++r) {
      float v = mx[m][r];
      v = fmaxf(v, __shfl_xor(v, 1));
      v = fmaxf(v, __shfl_xor(v, 2));
      v = fmaxf(v, __shfl_xor(v, 4));
      v = fmaxf(v, __shfl_xor(v, 8));
      mx[m][r] = v;
      sm[m][r] = 0.f;
    }
#pragma unroll
  for (int m = 0; m < 2; ++m)
#pragma unroll
    for (int n = 0; n < 12; ++n) {
      if (n < nlo || n >= nlo + 10) continue;
#pragma unroll
      for (int r = 0; r < 4; ++r) {
        float p = __expf(s[m][n][r] - mx[m][r]);
        s[m][n][r] = p;
        sm[m][r] += p;
      }
    }
#pragma unroll
  for (int m = 0; m < 2; ++m)
#pragma unroll
    for (int r = 0; r < 4; ++r) {
      float v = sm[m][r];
      v += __shfl_xor(v, 1);
      v += __shfl_xor(v, 2);
      v += __shfl_xor(v, 4);
      v += __shfl_xor(v, 8);
      inv[m][r] = 1.f / v;
    }

  // restage kbuf as vT tile (96 x 192 -> padded 200)
  __syncthreads();
  for (int it = 0; it < 9; ++it) {
    int c = t + 256 * it;
    int row = c / 24, seg = c - row * 24;
    int col0 = jbase + seg * 8; if (col0 < 0) col0 = 0;
    *(half8*)(kbuf + row * 200 + seg * 8) =
        *(const half8*)(vT + (size_t)row * 4096 + col0);
  }
  __syncthreads();

  // PV over live key-chunks (pbuf is wave-private: same-wave DS ordering, no barriers)
  f16* pw = pbuf[w];
  const int c6lo = nlo >> 1;           // 5 of 6 chunks live
  f32x4 o[2][6];
#pragma unroll
  for (int m = 0; m < 2; ++m)
#pragma unroll
    for (int dn = 0; dn < 6; ++dn)
      o[m][dn] = (f32x4){0.f, 0.f, 0.f, 0.f};

#pragma unroll
  for (int c6 = 0; c6 < 6; ++c6) {
    if (c6 < c6lo || c6 >= c6lo + 5) continue;
#pragma unroll
    for (int m = 0; m < 2; ++m)
#pragma unroll
      for (int nn = 0; nn < 2; ++nn)
#pragma unroll
        for (int r = 0; r < 4; ++r)
          pw[(m * 16 + kg * 4 + r) * 40 + nn * 16 + fr] = (f16)s[m][2 * c6 + nn][r];
    half8 ap0 = *(half8*)(pw + fr * 40 + kg * 8);
    half8 ap1 = *(half8*)(pw + (16 + fr) * 40 + kg * 8);
    __builtin_amdgcn_s_setprio(1);
#pragma unroll
    for (int dn = 0; dn < 6; ++dn) {
      half8 bv = *(half8*)(kbuf + (dn * 16 + fr) * 200 + c6 * 32 + kg * 8);
      o[0][dn] = MFMA16(ap0, bv, o[0][dn]);
      o[1][dn] = MFMA16(ap1, bv, o[1][dn]);
    }
    __builtin_amdgcn_s_setprio(0);
  }

#pragma unroll
  for (int m = 0; m < 2; ++m)
#pragma unroll
    for (int dn = 0; dn < 6; ++dn) {
      int col = h * QD + dn * 16 + fr;
#pragma unroll
      for (int r = 0; r < 4; ++r) {
        int row = i0 + q0 + m * 16 + kg * 4 + r;
        aout[(size_t)row * DM + col] = (f16)(o[m][dn][r] * inv[m][r]);
      }
    }
}

// ---------------------------------------------------------------------------
extern "C" void kernel_launch(void* const* d_in, const int* in_sizes, int n_in,
                              void* d_out, int out_size, void* d_ws, size_t ws_size,
                              hipStream_t stream) {
  const float* x    = (const float*)d_in[0];
  const float* Wqkv = (const float*)d_in[1];
  const float* bqkv = (const float*)d_in[2];
  const float* Wout = (const float*)d_in[3];
  const float* bout = (const float*)d_in[4];
  float* out = (float*)d_out;

  char* ws = (char*)d_ws;
  f16*   xh   = (f16*)(ws);                    // 6291456
  f16*   w1h  = (f16*)(ws + 6291456);          // 1572864
  f16*   w2h  = (f16*)(ws + 7864320);          // 1179648
  float* b1p  = (float*)(ws + 9043968);        // 4096
  float* ctab = (float*)(ws + 9048064);        // 786432
  float* stab = (float*)(ws + 9834496);        // 786432
  f16*   qh   = (f16*)(ws + 10620928);         // 6291456
  f16*   ql   = (f16*)(ws + 16912384);         // 6291456
  f16*   kh   = (f16*)(ws + 23203840);         // 786432
  f16*   kl   = (f16*)(ws + 23990272);         // 786432
  f16*   vT   = (f16*)(ws + 24776704);         // 786432
  f16*   aout = (f16*)(ws + 25563136);         // 6291456 -> total 31854592

  prep_kernel<<<dim3(5444), dim3(256), 0, stream>>>(x, Wqkv, bqkv, Wout,
                                                    xh, w1h, w2h, b1p, ctab, stab);
  gemm_qkv_rope<<<dim3(8, 64), dim3(256), 0, stream>>>(xh, w1h, b1p, ctab, stab,
                                                       qh, ql, kh, kl, vT);
  attn2_kernel<<<dim3(64, 4), dim3(256), 0, stream>>>(qh, ql, kh, kl, vT, aout);
  gemm_f16_tn<<<dim3(6, 64), dim3(256), 0, stream>>>(aout, w2h, bout, out, 768, 768);
}

// Round 5
// 68.384 us; speedup vs baseline: 5.2586x; 1.0967x over previous
//
#include <hip/hip_runtime.h>

typedef _Float16 f16;
typedef _Float16 half8 __attribute__((ext_vector_type(8)));
typedef _Float16 f16x2 __attribute__((ext_vector_type(2)));
typedef _Float16 f16x4 __attribute__((ext_vector_type(4)));
typedef float    f32x4 __attribute__((ext_vector_type(4)));

#define DM    768
#define QD    96
#define MFMA16(a,b,c) __builtin_amdgcn_mfma_f32_16x16x32_f16(a, b, c, 0, 0, 0)

// ---------------------------------------------------------------------------
__device__ __forceinline__ void async_copy16(const f16* g, f16* l) {
  __builtin_amdgcn_global_load_lds((const __attribute__((address_space(1))) void*)g,
                                   (__attribute__((address_space(3))) void*)l,
                                   16, 0, 0);
}

// ---------------------------------------------------------------------------
// merged prep: x cast (b<3072), weight cast/pad (b<4420), sincos table (rest)
// ---------------------------------------------------------------------------
__global__ __launch_bounds__(256) void prep_kernel(const float* __restrict__ x,
                                                   const float* __restrict__ Wqkv,
                                                   const float* __restrict__ bqkv,
                                                   const float* __restrict__ Wout,
                                                   f16* __restrict__ xh,
                                                   f16* __restrict__ w1h,
                                                   f16* __restrict__ w2h,
                                                   float* __restrict__ b1p,
                                                   float* __restrict__ ctab,
                                                   float* __restrict__ stab) {
  const int NW1 = 1024 * 768 / 4;
  const int NW2 = 768 * 768 / 4;
  int b = blockIdx.x;
  if (b < 3072) {                       // x cast: 4096*768/4 items
    int idx = b * 256 + threadIdx.x;
    f32x4 v = ((const f32x4*)x)[idx];
    f16x4 o;
    o[0] = (f16)v[0]; o[1] = (f16)v[1]; o[2] = (f16)v[2]; o[3] = (f16)v[3];
    ((f16x4*)xh)[idx] = o;
    return;
  }
  if (b < 4420) {                       // weights + bias
    int idx = (b - 3072) * 256 + threadIdx.x;
    if (idx < NW1) {
      int r = idx / 192;
      f16x4 o;
      if (r < 960) {
        f32x4 v = ((const f32x4*)Wqkv)[idx];
        o[0] = (f16)v[0]; o[1] = (f16)v[1]; o[2] = (f16)v[2]; o[3] = (f16)v[3];
      } else {
        o[0] = (f16)0.f; o[1] = (f16)0.f; o[2] = (f16)0.f; o[3] = (f16)0.f;
      }
      ((f16x4*)w1h)[idx] = o;
    } else if (idx < NW1 + NW2) {
      int j = idx - NW1;
      f32x4 v = ((const f32x4*)Wout)[j];
      f16x4 o;
      o[0] = (f16)v[0]; o[1] = (f16)v[1]; o[2] = (f16)v[2]; o[3] = (f16)v[3];
      ((f16x4*)w2h)[j] = o;
    } else {
      int j = idx - (NW1 + NW2);
      b1p[j] = (j < 960) ? bqkv[j] : 0.f;
    }
    return;
  }
  // sincos table: 4096 pos x 48 freqs (padded loop to 64, pow2 math)
  int idx = (b - 4420) * 256 + threadIdx.x;
  int pos = idx >> 6, f = idx & 63;
  if (f < 48) {
    float theta = exp2f((float)f * -0.27682734f);   // 10000^(-2f/96)
    float s, c;
    sincosf((float)pos * theta, &s, &c);
    ctab[pos * 48 + f] = c;
    stab[pos * 48 + f] = s;
  }
}

// ---------------------------------------------------------------------------
// shared GEMM macros: 64x128 tile, BK=64, 4 waves, double-buffered LDS,
// stage(next)->compute(cur)->sync pipeline (race-free: stage targets the
// buffer whose last readers all passed the PREVIOUS sync).
// LDS tiles are linear [rows][64] halves; the k-chunk is XOR-swizzled
// (chunk ^ (row&7)) on BOTH the global staging source and the ds_read
// address (rule #21: both-sides-or-neither) to cap bank conflicts.
// ---------------------------------------------------------------------------
#define GEMM_STAGE(NXT, K0)                                         \
  do {                                                              \
    async_copy16(Ap + (K0),           lA0 + (NXT) * 4096);          \
    async_copy16(Ap + 32 * K + (K0),  lA0 + (NXT) * 4096 + 2048);   \
    async_copy16(Bp + (K0),           lB0 + (NXT) * 8192);          \
    async_copy16(Bp + 32 * K + (K0),  lB0 + (NXT) * 8192 + 2048);   \
    async_copy16(Bp + 64 * K + (K0),  lB0 + (NXT) * 8192 + 4096);   \
    async_copy16(Bp + 96 * K + (K0),  lB0 + (NXT) * 8192 + 6144);   \
  } while (0)

#define GEMM_COMPUTE(BUF)                                                     \
  do {                                                                        \
    half8 a[4][2], b[2][2];                                                   \
    _Pragma("unroll")                                                         \
    for (int m = 0; m < 4; ++m) {                                             \
      int row = m * 16 + fr;                                                  \
      _Pragma("unroll")                                                       \
      for (int kk = 0; kk < 2; ++kk) {                                        \
        int c = (kk << 2) | kg;                                               \
        a[m][kk] = *(const half8*)&As[BUF][row * 64 + ((c ^ (row & 7)) << 3)];\
      }                                                                       \
    }                                                                         \
    _Pragma("unroll")                                                         \
    for (int n = 0; n < 2; ++n) {                                             \
      int row = w * 32 + n * 16 + fr;                                         \
      _Pragma("unroll")                                                       \
      for (int kk = 0; kk < 2; ++kk) {                                        \
        int c = (kk << 2) | kg;                                               \
        b[n][kk] = *(const half8*)&Bs[BUF][row * 64 + ((c ^ (row & 7)) << 3)];\
      }                                                                       \
    }                                                                         \
    _Pragma("unroll")                                                         \
    for (int m = 0; m < 4; ++m)                                               \
      _Pragma("unroll")                                                       \
      for (int n = 0; n < 2; ++n) {                                           \
        acc[m][n] = MFMA16(a[m][0], b[n][0], acc[m][n]);                      \
        acc[m][n] = MFMA16(a[m][1], b[n][1], acc[m][n]);                      \
      }                                                                       \
  } while (0)

#define GEMM_PROLOGUE_AND_LOOP                                      \
  __shared__ f16 As[2][64 * 64];                                    \
  __shared__ f16 Bs[2][128 * 64];                                   \
  const int t  = threadIdx.x;                                       \
  const int bm = blockIdx.y * 64;                                   \
  const int bn = blockIdx.x * 128;                                  \
  const int w  = t >> 6, l = t & 63;                                \
  const int fr = l & 15, kg = l >> 4;                               \
  f32x4 acc[4][2] = {};                                             \
  const int srow = t >> 3;                                          \
  const int skc  = ((t & 7) ^ (srow & 7)) << 3;  /* swizzled src k */ \
  const f16* Ap = A + (size_t)(bm + srow) * K + skc;                \
  const f16* Bp = B + (size_t)(bn + srow) * K + skc;                \
  f16* lA0 = &As[0][t * 8];                                         \
  f16* lB0 = &Bs[0][t * 8];                                         \
  const int nt = K >> 6; /* must be even */                         \
  GEMM_STAGE(0, 0);                                                 \
  __syncthreads();                                                  \
  for (int tk = 0; tk < nt; tk += 2) {                              \
    GEMM_STAGE(1, (tk + 1) << 6);                                   \
    GEMM_COMPUTE(0);                                                \
    __syncthreads();                                                \
    if (tk + 2 < nt) GEMM_STAGE(0, (tk + 2) << 6);                  \
    GEMM_COMPUTE(1);                                                \
    if (tk + 2 < nt) __syncthreads();                               \
  }

// ---------------------------------------------------------------------------
// GEMM2: C[M x ldc](f32) = A * B^T + bias (generic epilogue)
// ---------------------------------------------------------------------------
__global__ __launch_bounds__(256) void gemm_f16_tn(const f16* __restrict__ A,
                                                   const f16* __restrict__ B,
                                                   const float* __restrict__ bias,
                                                   float* __restrict__ C,
                                                   int K, int ldc) {
  GEMM_PROLOGUE_AND_LOOP
  const int r0 = kg * 4;
#pragma unroll
  for (int n = 0; n < 2; ++n) {
    int col = bn + w * 32 + n * 16 + fr;
    float bv = bias[col];
#pragma unroll
    for (int m = 0; m < 4; ++m) {
      int row = bm + m * 16 + r0;
#pragma unroll
      for (int r = 0; r < 4; ++r)
        C[(size_t)(row + r) * ldc + col] = acc[m][n][r] + bv;
    }
  }
}

// ---------------------------------------------------------------------------
// GEMM1 fused: qkv GEMM + bias + RoPE (table) + f16 hi/lo split + V transpose.
// Columns: [0,96)=k -> kh/kl; [96,192)=v -> vT; [192,960)=q -> qh/ql; >=960 pad.
// RoPE pair (2f,2f+1) = adjacent cols = lanes (fr, fr^1): shfl_xor exchange.
// ---------------------------------------------------------------------------
__global__ __launch_bounds__(256) void gemm_qkv_rope(const f16* __restrict__ A,
                                                     const f16* __restrict__ B,
                                                     const float* __restrict__ bias,
                                                     const float* __restrict__ ctab,
                                                     const float* __restrict__ stab,
                                                     f16* __restrict__ qh,
                                                     f16* __restrict__ ql,
                                                     f16* __restrict__ kh,
                                                     f16* __restrict__ kl,
                                                     f16* __restrict__ vT) {
  const int K = 768;
  GEMM_PROLOGUE_AND_LOOP
  const int r0 = kg * 4;
#pragma unroll
  for (int n = 0; n < 2; ++n) {
    int col = bn + w * 32 + n * 16 + fr;
    float bv = bias[col];
    int seg = (col * 683) >> 16;        // col / 96
    int segoff = col - seg * 96;
    int f = segoff >> 1;
    bool odd = col & 1;
#pragma unroll
    for (int m = 0; m < 4; ++m) {
      int row = bm + m * 16 + r0;
#pragma unroll
      for (int r = 0; r < 4; ++r) {
        float v = acc[m][n][r] + bv;
        float p = __shfl_xor(v, 1);     // partner column of the rope pair
        if (seg == 1) {                 // v column
          vT[(size_t)(col - 96) * 4096 + (row + r)] = (f16)v;
        } else if (col < 960) {         // k or q column: rope
          float c = ctab[(row + r) * 48 + f];
          float s = stab[(row + r) * 48 + f];
          float e = odd ? p : v;
          float o = odd ? v : p;
          float res = odd ? (e * s + o * c) : (e * c - o * s);
          f16 hi = (f16)res;
          f16 lo = (f16)(res - (float)hi);
          if (seg == 0) {
            kh[(size_t)(row + r) * QD + col] = hi;
            kl[(size_t)(row + r) * QD + col] = lo;
          } else {
            int qc = col - 192;
            qh[(size_t)(row + r) * DM + qc] = hi;
            ql[(size_t)(row + r) * DM + qc] = lo;
          }
        }
      }
    }
  }
}

// ---------------------------------------------------------------------------
// MFMA windowed attention. Block = 64-query tile x 2 heads, 4 waves.
// Wave = 1 head x 32 queries x 192 keys; chunk pruning (10 of 12 can be live);
// split-f16 QK^T; in-register masked softmax; PV via per-wave LDS round-trip.
// ---------------------------------------------------------------------------
__global__ __launch_bounds__(256) void attn2_kernel(const f16* __restrict__ qh,
                                                    const f16* __restrict__ ql,
                                                    const f16* __restrict__ kh,
                                                    const f16* __restrict__ kl,
                                                    const f16* __restrict__ vT,
                                                    f16* __restrict__ aout) {
  __shared__ f16 kbuf[192 * 104];      // K_hi tile; later vT tile [96][200]
  __shared__ f16 pbuf[4][32 * 40];     // per-wave P chunk (wave-private)
  const int t  = threadIdx.x, w = t >> 6, l = t & 63;
  const int fr = l & 15, kg = l >> 4;
  const int i0 = blockIdx.x * 64;
  const int h  = blockIdx.y * 2 + (w >> 1);
  const int q0 = (w & 1) * 32;
  const int jbase = i0 - 128;
  const int nlo = (w & 1) ? 2 : 0;     // live key-chunks: [nlo, nlo+10)

  // stage K_hi tile (192 x 96 -> padded 104)
  for (int it = 0; it < 9; ++it) {
    int c = t + 256 * it;
    int row = c / 12, seg = c - row * 12;
    int jabs = jbase + row; if (jabs < 0) jabs = 0;
    *(half8*)(kbuf + row * 104 + seg * 8) =
        *(const half8*)(kh + (size_t)jabs * QD + seg * 8);
  }

  half8 a_h[2][3], a_l[2][3];
#pragma unroll
  for (int m = 0; m < 2; ++m) {
    size_t qoff = (size_t)(i0 + q0 + m * 16 + fr) * DM + h * QD;
#pragma unroll
    for (int kc = 0; kc < 3; ++kc) {
      a_h[m][kc] = *(const half8*)(qh + qoff + kc * 32 + kg * 8);
      a_l[m][kc] = *(const half8*)(ql + qoff + kc * 32 + kg * 8);
    }
  }
  __syncthreads();

  // S = Q K^T  (hi*hi + lo*hi + hi*lo)
  f32x4 s[2][12];
#pragma unroll
  for (int m = 0; m < 2; ++m)
#pragma unroll
    for (int n = 0; n < 12; ++n)
      s[m][n] = (f32x4){0.f, 0.f, 0.f, 0.f};

  __builtin_amdgcn_s_setprio(1);
#pragma unroll
  for (int n = 0; n < 12; ++n) {
    if (n < nlo || n >= nlo + 10) continue;
    int krow = n * 16 + fr;
    int jabs = jbase + krow; if (jabs < 0) jabs = 0;
#pragma unroll
    for (int kc = 0; kc < 3; ++kc) {
      half8 b_h = *(const half8*)(kbuf + krow * 104 + kc * 32 + kg * 8);
      half8 b_l = *(const half8*)(kl + (size_t)jabs * QD + kc * 32 + kg * 8);
      s[0][n] = MFMA16(a_h[0][kc], b_h, s[0][n]);
      s[1][n] = MFMA16(a_h[1][kc], b_h, s[1][n]);
      s[0][n] = MFMA16(a_l[0][kc], b_h, s[0][n]);
      s[1][n] = MFMA16(a_l[1][kc], b_h, s[1][n]);
      s[0][n] = MFMA16(a_h[0][kc], b_l, s[0][n]);
      s[1][n] = MFMA16(a_h[1][kc], b_l, s[1][n]);
    }
  }
  __builtin_amdgcn_s_setprio(0);

  // mask + scale + softmax
  const int jmin = (i0 < 128) ? (128 - i0) : 0;
  const float scale = 9.79795897113271f;
  float mx[2][4], sm[2][4], inv[2][4];
#pragma unroll
  for (int m = 0; m < 2; ++m)
#pragma unroll
    for (int r = 0; r < 4; ++r) mx[m][r] = -1e30f;

#pragma unroll
  for (int m = 0; m < 2; ++m)
#pragma unroll
    for (int n = 0; n < 12; ++n) {
      if (n < nlo || n >= nlo + 10) continue;
      int jloc = n * 16 + fr;
#pragma unroll
      for (int r = 0; r < 4; ++r) {
        int iloc = q0 + m * 16 + kg * 4 + r;
        bool valid = (jloc > iloc) && (jloc <= iloc + 128) && (jloc >= jmin);
        float v = valid ? s[m][n][r] * scale : -1e30f;
        s[m][n][r] = v;
        mx[m][r] = fmaxf(mx[m][r], v);
      }
    }
#pragma unroll
  for (int m = 0; m < 2; ++m)
#pragma unroll
    for (int r = 0; r < 4; ++r) {
      float v = mx[m][r];
      v = fmaxf(v, __shfl_xor(v, 1));
      v = fmaxf(v, __shfl_xor(v, 2));
      v = fmaxf(v, __shfl_xor(v, 4));
      v = fmaxf(v, __shfl_xor(v, 8));
      mx[m][r] = v;
      sm[m][r] = 0.f;
    }
#pragma unroll
  for (int m = 0; m < 2; ++m)
#pragma unroll
    for (int n = 0; n < 12; ++n) {
      if (n < nlo || n >= nlo + 10) continue;
#pragma unroll
      for (int r = 0; r < 4; ++r) {
        float p = __expf(s[m][n][r] - mx[m][r]);
        s[m][n][r] = p;
        sm[m][r] += p;
      }
    }
#pragma unroll
  for (int m = 0; m < 2; ++m)
#pragma unroll
    for (int r = 0; r < 4; ++r) {
      float v = sm[m][r];
      v += __shfl_xor(v, 1);
      v += __shfl_xor(v, 2);
      v += __shfl_xor(v, 4);
      v += __shfl_xor(v, 8);
      inv[m][r] = 1.f / v;
    }

  // restage kbuf as vT tile (96 x 192 -> padded 200)
  __syncthreads();
  for (int it = 0; it < 9; ++it) {
    int c = t + 256 * it;
    int row = c / 24, seg = c - row * 24;
    int col0 = jbase + seg * 8; if (col0 < 0) col0 = 0;
    *(half8*)(kbuf + row * 200 + seg * 8) =
        *(const half8*)(vT + (size_t)row * 4096 + col0);
  }
  __syncthreads();

  // PV over live key-chunks (pbuf is wave-private: same-wave DS ordering, no barriers)
  f16* pw = pbuf[w];
  const int c6lo = nlo >> 1;           // 5 of 6 chunks live
  f32x4 o[2][6];
#pragma unroll
  for (int m = 0; m < 2; ++m)
#pragma unroll
    for (int dn = 0; dn < 6; ++dn)
      o[m][dn] = (f32x4){0.f, 0.f, 0.f, 0.f};

#pragma unroll
  for (int c6 = 0; c6 < 6; ++c6) {
    if (c6 < c6lo || c6 >= c6lo + 5) continue;
#pragma unroll
    for (int m = 0; m < 2; ++m)
#pragma unroll
      for (int nn = 0; nn < 2; ++nn)
#pragma unroll
        for (int r = 0; r < 4; ++r)
          pw[(m * 16 + kg * 4 + r) * 40 + nn * 16 + fr] = (f16)s[m][2 * c6 + nn][r];
    half8 ap0 = *(half8*)(pw + fr * 40 + kg * 8);
    half8 ap1 = *(half8*)(pw + (16 + fr) * 40 + kg * 8);
    __builtin_amdgcn_s_setprio(1);
#pragma unroll
    for (int dn = 0; dn < 6; ++dn) {
      half8 bv = *(half8*)(kbuf + (dn * 16 + fr) * 200 + c6 * 32 + kg * 8);
      o[0][dn] = MFMA16(ap0, bv, o[0][dn]);
      o[1][dn] = MFMA16(ap1, bv, o[1][dn]);
    }
    __builtin_amdgcn_s_setprio(0);
  }

#pragma unroll
  for (int m = 0; m < 2; ++m)
#pragma unroll
    for (int dn = 0; dn < 6; ++dn) {
      int col = h * QD + dn * 16 + fr;
#pragma unroll
      for (int r = 0; r < 4; ++r) {
        int row = i0 + q0 + m * 16 + kg * 4 + r;
        aout[(size_t)row * DM + col] = (f16)(o[m][dn][r] * inv[m][r]);
      }
    }
}

// ---------------------------------------------------------------------------
extern "C" void kernel_launch(void* const* d_in, const int* in_sizes, int n_in,
                              void* d_out, int out_size, void* d_ws, size_t ws_size,
                              hipStream_t stream) {
  const float* x    = (const float*)d_in[0];
  const float* Wqkv = (const float*)d_in[1];
  const float* bqkv = (const float*)d_in[2];
  const float* Wout = (const float*)d_in[3];
  const float* bout = (const float*)d_in[4];
  float* out = (float*)d_out;

  char* ws = (char*)d_ws;
  f16*   xh   = (f16*)(ws);                    // 6291456
  f16*   w1h  = (f16*)(ws + 6291456);          // 1572864
  f16*   w2h  = (f16*)(ws + 7864320);          // 1179648
  float* b1p  = (float*)(ws + 9043968);        // 4096
  float* ctab = (float*)(ws + 9048064);        // 786432
  float* stab = (float*)(ws + 9834496);        // 786432
  f16*   qh   = (f16*)(ws + 10620928);         // 6291456
  f16*   ql   = (f16*)(ws + 16912384);         // 6291456
  f16*   kh   = (f16*)(ws + 23203840);         // 786432
  f16*   kl   = (f16*)(ws + 23990272);         // 786432
  f16*   vT   = (f16*)(ws + 24776704);         // 786432
  f16*   aout = (f16*)(ws + 25563136);         // 6291456 -> total 31854592

  prep_kernel<<<dim3(5444), dim3(256), 0, stream>>>(x, Wqkv, bqkv, Wout,
                                                    xh, w1h, w2h, b1p, ctab, stab);
  gemm_qkv_rope<<<dim3(8, 64), dim3(256), 0, stream>>>(xh, w1h, b1p, ctab, stab,
                                                       qh, ql, kh, kl, vT);
  attn2_kernel<<<dim3(64, 4), dim3(256), 0, stream>>>(qh, ql, kh, kl, vT, aout);
  gemm_f16_tn<<<dim3(6, 64), dim3(256), 0, stream>>>(aout, w2h, bout, out, 768, 768);
}